// Round 21
// baseline (531.863 us; speedup 1.0000x reference)
//
#include <hip/hip_runtime.h>
#include <math.h>

#define D_MODEL 1024
#define D_FF    4096
#define NEXP    8
#define NTOK    8192
#define NASSIGN (NTOK*2)
#define NGBLK   (NTOK/4)   // gating blocks (4 tokens/block)

using short8 = __attribute__((ext_vector_type(8))) short;
using short4v = __attribute__((ext_vector_type(4))) short;
using f32x4  = __attribute__((ext_vector_type(4))) float;

__device__ __forceinline__ short f2bf(float f) {
  unsigned u = __float_as_uint(f);
  unsigned r = (u + 0x7fffu + ((u >> 16) & 1u)) >> 16;
  return (short)r;
}
__device__ __forceinline__ float bf2f(unsigned short u) {
  return __uint_as_float(((unsigned)u) << 16);
}

__device__ __forceinline__ void gload_lds16(const void* g, void* l) {
  __builtin_amdgcn_global_load_lds((const __attribute__((address_space(1))) void*)g,
                                   (__attribute__((address_space(3))) void*)l, 16, 0, 0);
}

// fast erf-gelu: Abramowitz-Stegun 7.1.26, |eps| <= 1.5e-7
__device__ __forceinline__ float gelu_f(float x) {
  float z = 0.70710678118f * x;
  float a = fabsf(z);
  float t = 1.0f / (1.0f + 0.3275911f * a);
  float p = t * (0.254829592f + t * (-0.284496736f + t * (1.421413741f +
            t * (-1.453152027f + t * 1.061405429f))));
  float er = 1.0f - p * __expf(-a * a);
  er = copysignf(er, z);
  return 0.5f * x * (1.0f + er);
}

// ========== fused prologue: W1-transpose | W2-transpose | gating, by blockIdx range ==========
__global__ __launch_bounds__(256) void prologue_kernel(
    const float* __restrict__ W1, short* __restrict__ w1t,
    const float* __restrict__ W2, short* __restrict__ w2t,
    const float* __restrict__ x, const float* __restrict__ Wg,
    int* __restrict__ assign_e, float* __restrict__ assign_w,
    int* __restrict__ cnt_part, float* __restrict__ psum_part,
    ushort4* __restrict__ xb4)
{
  __shared__ float t[64][70];          // transpose slab (17.9 KB)
  __shared__ float l_ps[NEXP];         // gating partials (coexist, tiny)
  __shared__ int   l_cnt[NEXP];
  int bid = blockIdx.x;
  int tid = threadIdx.x;

  if (bid < 16384) {
    // ---------------- transpose + convert (float2 loads, pad-70, full-line stores) ----------------
    const float* in; short* out; int R, C, cx, cy, e;
    if (bid < 8192) { in = W1; out = w1t; R = D_MODEL; C = D_FF;
                      cx = bid & 63; cy = (bid >> 6) & 15; e = bid >> 10; }
    else            { int lb = bid - 8192; in = W2; out = w2t; R = D_FF; C = D_MODEL;
                      cx = lb & 15;  cy = (lb >> 4) & 63;  e = lb >> 10; }
    size_t base = (size_t)e * R * C;
    int r0 = cy * 64, c0 = cx * 64;
    int lr = tid >> 5, lc2 = tid & 31;
#pragma unroll
    for (int j = 0; j < 8; ++j) {
      int rr = lr + j * 8;
      float2 v = *(const float2*)&in[base + (size_t)(r0 + rr) * C + c0 + lc2 * 2];
      *(float2*)&t[rr][lc2 * 2] = v;
    }
    __syncthreads();
#pragma unroll
    for (int p = 0; p < 2; ++p) {
      int oc = p * 32 + (tid >> 3);       // output row (input col)
      int rseg = (tid & 7) * 8;           // 8 consecutive R-elements
      short8 v;
#pragma unroll
      for (int q = 0; q < 8; ++q) v[q] = f2bf(t[rseg + q][oc]);
      *(short8*)&out[base + (size_t)(c0 + oc) * R + r0 + rseg] = v;
    }
    return;
  }

  // ---------------- gating: one wave per token; also emits xb (bf16 copy of x) ----------------
  int gb = bid - 16384;
  int wv = tid >> 6, lane = tid & 63;
  if (tid < NEXP) { l_ps[tid] = 0.f; l_cnt[tid] = 0; }
  __syncthreads();

  int tk = gb * 4 + wv;
  const float4* xr = (const float4*)(x + (size_t)tk * D_MODEL);
  float acc[NEXP];
#pragma unroll
  for (int e = 0; e < NEXP; ++e) acc[e] = 0.f;
#pragma unroll
  for (int i = 0; i < 4; ++i) {
    int c4 = lane + 64 * i;
    float4 v = xr[c4];
    ushort4 o;
    o.x = (unsigned short)f2bf(v.x); o.y = (unsigned short)f2bf(v.y);
    o.z = (unsigned short)f2bf(v.z); o.w = (unsigned short)f2bf(v.w);
    xb4[(size_t)tk * 256 + c4] = o;
    const float* wr = Wg + c4 * 4 * NEXP;
#pragma unroll
    for (int j = 0; j < 4; ++j) {
      float xv = (&v.x)[j];
#pragma unroll
      for (int e = 0; e < NEXP; ++e) acc[e] += xv * wr[j * NEXP + e];
    }
  }
#pragma unroll
  for (int off = 32; off; off >>= 1)
#pragma unroll
    for (int e = 0; e < NEXP; ++e) acc[e] += __shfl_down(acc[e], off);

  if (lane == 0) {
    float m = acc[0];
#pragma unroll
    for (int e = 1; e < NEXP; ++e) m = fmaxf(m, acc[e]);
    float p[NEXP], s = 0.f;
#pragma unroll
    for (int e = 0; e < NEXP; ++e) { p[e] = expf(acc[e] - m); s += p[e]; }
    float inv = 1.f / s;
#pragma unroll
    for (int e = 0; e < NEXP; ++e) p[e] *= inv;
    int i0 = 0; float v0 = p[0];
#pragma unroll
    for (int e = 1; e < NEXP; ++e) if (p[e] > v0) { v0 = p[e]; i0 = e; }
    int i1 = -1; float v1 = -1.f;
#pragma unroll
    for (int e = 0; e < NEXP; ++e) if (e != i0 && p[e] > v1) { v1 = p[e]; i1 = e; }
    float denom = 1.f / (v0 + v1 + 1e-9f);
    assign_e[2 * tk] = i0;     assign_w[2 * tk] = v0 * denom;
    assign_e[2 * tk + 1] = i1; assign_w[2 * tk + 1] = v1 * denom;
    atomicAdd(&l_cnt[i0], 1);
    atomicAdd(&l_cnt[i1], 1);
#pragma unroll
    for (int e = 0; e < NEXP; ++e) atomicAdd(&l_ps[e], p[e]);
  }
  __syncthreads();
  if (tid < NEXP) {
    psum_part[gb * NEXP + tid] = l_ps[tid];
    cnt_part[gb * NEXP + tid] = l_cnt[tid];
  }
}

// ---------------- scan: reduce partials -> cnt/offs + cursor zero + aux loss ----------------
__global__ __launch_bounds__(256) void scan_kernel(const int* __restrict__ cnt_part, const float* __restrict__ psum_part,
                                                   int* __restrict__ cnt, int* __restrict__ offs,
                                                   int* __restrict__ cursor, float* __restrict__ aux_out) {
  __shared__ float sp[256];
  __shared__ int   sc[256];
  int tid = threadIdx.x;
  int e = tid & 7, c = tid >> 3;
  float fs = 0.f; int is = 0;
  for (int b = c; b < NGBLK; b += 32) {
    fs += psum_part[b * NEXP + e];
    is += cnt_part[b * NEXP + e];
  }
  sp[tid] = fs; sc[tid] = is;
  __syncthreads();
  if (tid < NEXP) {
    float f = 0.f; int n = 0;
    for (int c2 = 0; c2 < 32; ++c2) { f += sp[c2 * 8 + tid]; n += sc[c2 * 8 + tid]; }
    cnt[tid] = n; sp[tid] = f;
    cursor[tid] = 0;
  }
  __syncthreads();
  if (tid == 0) {
    int o = 0; float aux = 0.f;
    for (int e2 = 0; e2 < NEXP; ++e2) {
      offs[e2] = o; o += cnt[e2];
      aux += (float)cnt[e2] * sp[e2];
    }
    aux_out[0] = aux * (float)NEXP / ((float)NTOK * (float)NTOK);
  }
}

// ---------------- scatter: compact assignments per expert ----------------
__global__ __launch_bounds__(256) void scatter_kernel(const int* __restrict__ assign_e,
                                                      const int* __restrict__ offs, int* __restrict__ cursor,
                                                      int* __restrict__ slot_tok, int* __restrict__ slot_of) {
  __shared__ int lhist[NEXP], lbase[NEXP];
  int tid = threadIdx.x;
  int a = blockIdx.x * 256 + tid;
  if (tid < NEXP) lhist[tid] = 0;
  __syncthreads();
  int e = assign_e[a];
  int lp = atomicAdd(&lhist[e], 1);
  __syncthreads();
  if (tid < NEXP) lbase[tid] = atomicAdd(&cursor[tid], lhist[tid]);
  __syncthreads();
  int s = offs[e] + lbase[e] + lp;
  slot_tok[s] = a >> 1;
  slot_of[a] = s;
}

// ========== 256x256 GEMM, lead-7 / vmcnt(6), MINIMAL 3-barrier schedule (R21) ==========
// Hazard audit (write vs prior conflicting reads, in-order lgkm retirement):
//  q0-end barrier : entry B/A@cx0 reads retired before each wave's q0 MFMA -> STAGE(0/1,t+2)
//                   (B-regions of buf t) issued at q1/q2 are safe after it.
//  q2-end barrier : afA@cx1 (q1-prefetch) retired before q2 MFMA -> STAGE(2,t+2) (A-s02 buf t)
//                   at q3 safe; concurrent q3 afB reads touch A-s13 only (disjoint).
//  q3-end barrier : after boundary vmcnt; publishes tile t+1 staging + protects next-q0
//                   STAGE(3,t+2) (A-s13 buf t) from this tile's afB@cx1 reads.
// Pre-MFMA barriers and q1-end protect nothing -> removed (5 fewer barriers/tile).
// s_setprio removed (R20: +17 us). No wave role-split enforced -> waves may drift within a
// tile, overlapping one wave's MFMA with another's stage/ds_read.
template<int KD, int ND, int RT, int EPI, bool RTOUT>
__global__ __launch_bounds__(512, 2) void gemm8p(
    const short* __restrict__ Asrc, const short* __restrict__ Bsrc,
    const float* __restrict__ bias, const int* __restrict__ slot_tok,
    const int* __restrict__ cnt, const int* __restrict__ offs,
    short* __restrict__ OutP)
{
  constexpr int NT = KD / 64;          // K-tiles
  constexpr int NP = ND / 256;         // N panels
  constexpr int NPAN = NEXP * NP / 8;  // panels per XCD
  extern __shared__ char ldsb[];       // [buf][A 32K | B 32K]

  int bid = blockIdx.x;
  int x = bid & 7, j = bid >> 3;
  int k, rt;
  if (RTOUT) { rt = j / NPAN; k = j - rt * NPAN; }   // duds trail the grid
  else       { k = j / RT;    rt = j - k * RT; }     // rt-inner: panel L2 sharing
  int ft = k % NP;
  int e = (x + k) & 7;
  int cn = cnt[e];
  if (rt * 256 >= cn) return;
  int off = offs[e];
  int tid = threadIdx.x, l = tid & 63, w = tid >> 6;
  int wm = w >> 2, wn = w & 3;         // 2M x 4N
  int l15 = l & 15, kh = l >> 4;

  // ---- staging sources: stripe s, row (tid>>3), chunk pre-swizzled ----
  int srw = tid >> 3;
  int swz = ((tid & 7) ^ (srw & 7)) * 8;   // shorts
  const short* ar[4];
  const short* br[4];
#pragma unroll
  for (int s = 0; s < 4; ++s) {
    int gr = rt * 256 + s * 64 + srw;
    int ic = gr < cn ? gr : cn - 1;
    if (EPI == 0) ar[s] = Asrc + (size_t)slot_tok[off + ic] * KD + swz;
    else          ar[s] = Asrc + (size_t)(off + ic) * KD + swz;
    br[s] = Bsrc + (size_t)e * ND * KD + (size_t)(ft * 256 + s * 64 + srw) * KD + swz;
  }

#define STAGE(P, TAU) do {                                                        \
    int _b = (TAU) & 1;                                                           \
    const short* _p0 = ((P) >= 2 ? ar : br)[(P) & 1];                             \
    const short* _p1 = ((P) >= 2 ? ar : br)[((P) & 1) + 2];                       \
    char* _d = ldsb + _b * 65536 + ((P) >= 2 ? 0 : 32768);                        \
    gload_lds16(_p0 + (size_t)(TAU) * 64, _d + ((P) & 1) * 8192 + tid * 16);      \
    gload_lds16(_p1 + (size_t)(TAU) * 64, _d + (((P) & 1) + 2) * 8192 + tid * 16);\
  } while (0)

  // ---- prologue: 7 half-tiles (tile0 all parts + tile1 P0,P1,P2) ----
  STAGE(0, 0); STAGE(1, 0); STAGE(2, 0); STAGE(3, 0);
  STAGE(0, 1); STAGE(1, 1); STAGE(2, 1);
  asm volatile("s_waitcnt vmcnt(6)" ::: "memory");  // tile0 (8 loads) landed
  __builtin_amdgcn_s_barrier();

  int cx0 = ((0 * 4 + kh) ^ (l15 & 7)) << 4;   // byte XOR-offset for kk=0
  int cx1 = ((1 * 4 + kh) ^ (l15 & 7)) << 4;   // kk=1
  int arow = (wm * 128 + l15) << 7;            // byte row base for A reads
  int brow = (wn * 64 + l15) << 7;
  f32x4 acc[8][4] = {};
  short8 bq0[4], bq1[4], afA[4], afB[4];

  for (int t = 0; t < NT; ++t) {
    const char* Ab = ldsb + (t & 1) * 65536;
    const char* Bb = Ab + 32768;
    // ---- tile-entry reads: ALL B (kk0 + kk1) + A(mh0,kk0) ----
#pragma unroll
    for (int n = 0; n < 4; ++n) bq0[n] = *(const short8*)(Bb + brow + (n << 11) + cx0);
#pragma unroll
    for (int n = 0; n < 4; ++n) bq1[n] = *(const short8*)(Bb + brow + (n << 11) + cx1);
#pragma unroll
    for (int m = 0; m < 4; ++m) afA[m] = *(const short8*)(Ab + arow + ((m * 16) << 7) + cx0);
    // ---- q0: stage P3(t+1); prefetch A(mh1,kk0); MFMA(bq0, afA -> acc[0..3]); q0-end barrier ----
    if (t + 1 < NT) STAGE(3, t + 1);
#pragma unroll
    for (int m = 0; m < 4; ++m) afB[m] = *(const short8*)(Ab + arow + ((64 + m * 16) << 7) + cx0);
#pragma unroll
    for (int m = 0; m < 4; ++m)
#pragma unroll
      for (int n = 0; n < 4; ++n)
        acc[m][n] = __builtin_amdgcn_mfma_f32_16x16x32_bf16(bq0[n], afA[m], acc[m][n], 0, 0, 0);
    __builtin_amdgcn_s_barrier();
    // ---- q1: stage P0(t+2); prefetch A(mh0,kk1); MFMA(bq0, afB -> acc[4..7]); no barrier ----
    if (t + 2 < NT) STAGE(0, t + 2);
#pragma unroll
    for (int m = 0; m < 4; ++m) afA[m] = *(const short8*)(Ab + arow + ((m * 16) << 7) + cx1);
#pragma unroll
    for (int m = 0; m < 4; ++m)
#pragma unroll
      for (int n = 0; n < 4; ++n)
        acc[4 + m][n] = __builtin_amdgcn_mfma_f32_16x16x32_bf16(bq0[n], afB[m], acc[4 + m][n], 0, 0, 0);
    // ---- q2: stage P1(t+2); prefetch A(mh1,kk1); MFMA(bq1, afA -> acc[0..3]); q2-end barrier ----
    if (t + 2 < NT) STAGE(1, t + 2);
#pragma unroll
    for (int m = 0; m < 4; ++m) afB[m] = *(const short8*)(Ab + arow + ((64 + m * 16) << 7) + cx1);
#pragma unroll
    for (int m = 0; m < 4; ++m)
#pragma unroll
      for (int n = 0; n < 4; ++n)
        acc[m][n] = __builtin_amdgcn_mfma_f32_16x16x32_bf16(bq1[n], afA[m], acc[m][n], 0, 0, 0);
    __builtin_amdgcn_s_barrier();
    // ---- q3: stage P2(t+2); MFMA(bq1, afB -> acc[4..7]); boundary vmcnt; q3-end barrier ----
    if (t + 2 < NT) STAGE(2, t + 2);
#pragma unroll
    for (int m = 0; m < 4; ++m)
#pragma unroll
      for (int n = 0; n < 4; ++n)
        acc[4 + m][n] = __builtin_amdgcn_mfma_f32_16x16x32_bf16(bq1[n], afB[m], acc[4 + m][n], 0, 0, 0);
    if (t < NT - 2)       { asm volatile("s_waitcnt vmcnt(6)" ::: "memory"); }
    else if (t == NT - 2) { asm volatile("s_waitcnt vmcnt(0)" ::: "memory"); }
    __builtin_amdgcn_s_barrier();
  }
#undef STAGE

  // ---- epilogue: bf16 via per-wave DOUBLE LDS slab -> full-line 16B stores (EPI0 adds gelu) ----
  int ftb = ft * 256;
  f32x4 b4[4];
#pragma unroll
  for (int n = 0; n < 4; ++n) b4[n] = *(const f32x4*)&bias[e * ND + ftb + wn * 64 + n * 16 + kh * 4];

  char* slab0 = ldsb + w * 4096;       // per-wave 2 x 2 KB (alternating by mi&1)
#pragma unroll
  for (int mi = 0; mi < 8; ++mi) {
    char* slab = slab0 + (mi & 1) * 2048;
#pragma unroll
    for (int n = 0; n < 4; ++n) {
      short4v h;
#pragma unroll
      for (int jj = 0; jj < 4; ++jj) {
        float v = acc[mi][n][jj] + b4[n][jj];
        if (EPI == 0) v = gelu_f(v);
        h[jj] = f2bf(v);
      }
      int chunk = n * 2 + (kh >> 1);
      *(short4v*)(slab + l15 * 128 + ((chunk ^ (l15 & 7)) << 4) + ((kh & 1) << 3)) = h;
    }
    int tr = l >> 2;
    int tok = rt * 256 + wm * 128 + mi * 16 + tr;
    if (tok < cn) {
#pragma unroll
      for (int cc = 0; cc < 2; ++cc) {
        int c2 = (l & 3) * 2 + cc;
        short8 v = *(const short8*)(slab + tr * 128 + ((c2 ^ (tr & 7)) << 4));
        *(short8*)&OutP[(size_t)(off + tok) * ND + ftb + wn * 64 + c2 * 8] = v;
      }
    }
  }
}

// ---------------- combine: out[t] = w0*y[s0] + w1*y[s1]  (y is bf16; 4 tokens/block) ----------------
__global__ __launch_bounds__(256) void combine_kernel(const unsigned short* __restrict__ y,
                                                      const int* __restrict__ slot_of,
                                                      const float* __restrict__ assign_w, float* __restrict__ out) {
  int tb = blockIdx.x * 4;
#pragma unroll
  for (int q = 0; q < 4; ++q) {
    int t = tb + q;
    int d4 = threadIdx.x;
    int s0 = slot_of[2 * t], s1 = slot_of[2 * t + 1];
    float w0 = assign_w[2 * t], w1 = assign_w[2 * t + 1];
    ushort4 a = ((const ushort4*)(y + (size_t)s0 * D_MODEL))[d4];
    ushort4 b = ((const ushort4*)(y + (size_t)s1 * D_MODEL))[d4];
    float4 o;
    o.x = w0 * bf2f(a.x) + w1 * bf2f(b.x);
    o.y = w0 * bf2f(a.y) + w1 * bf2f(b.y);
    o.z = w0 * bf2f(a.z) + w1 * bf2f(b.z);
    o.w = w0 * bf2f(a.w) + w1 * bf2f(b.w);
    ((float4*)(out + (size_t)t * D_MODEL))[d4] = o;
  }
}

extern "C" void kernel_launch(void* const* d_in, const int* in_sizes, int n_in,
                              void* d_out, int out_size, void* d_ws, size_t ws_size,
                              hipStream_t stream) {
  const float* x  = (const float*)d_in[0];
  const float* Wg = (const float*)d_in[1];
  const float* W1 = (const float*)d_in[2];
  const float* b1 = (const float*)d_in[3];
  const float* W2 = (const float*)d_in[4];
  const float* b2 = (const float*)d_in[5];
  float* out = (float*)d_out;
  char* ws = (char*)d_ws;

  // workspace layout (~285.6 MB)
  short* xb       = (short*)(ws);                       // 16,777,216 B
  short* w1t      = (short*)(ws + 16777216);            // 67,108,864 B  [e][f][k] bf16
  short* y        = (short*)(ws + 16777216);            // aliases w1t (dead after gemm1): 16384x1024 bf16
  short* w2t      = (short*)(ws + 83886080);            // 67,108,864 B  [e][d][ff] bf16
  short* H        = (short*)(ws + 150994944);           // 134,217,728 B 16384 x 4096 bf16
  int*   slot_tok = (int*)  (ws + 285212672);
  int*   assign_e = (int*)  (ws + 285278208);
  float* assign_w = (float*)(ws + 285343744);
  int*   slot_of  = (int*)  (ws + 285409280);
  int*   cnt_part = (int*)  (ws + 285474816);
  float* psum_part= (float*)(ws + 285540352);
  int*   ctrl     = (int*)  (ws + 285605888);
  int* cnt = ctrl; int* cursor = ctrl + 8; int* offs = ctrl + 16;

  hipFuncSetAttribute(reinterpret_cast<const void*>(&gemm8p<D_MODEL, D_FF, 12, 0, false>),
                      hipFuncAttributeMaxDynamicSharedMemorySize, 131072);
  hipFuncSetAttribute(reinterpret_cast<const void*>(&gemm8p<D_FF, D_MODEL, 12, 1, true>),
                      hipFuncAttributeMaxDynamicSharedMemorySize, 131072);

  // fused prologue: 8192 W1-tiles + 8192 W2-tiles + 2048 gating blocks = 18432 blocks, 1 launch
  prologue_kernel<<<16384 + NGBLK, 256, 0, stream>>>(W1, w1t, W2, w2t, x, Wg,
                                                     assign_e, assign_w, cnt_part, psum_part,
                                                     (ushort4*)xb);
  scan_kernel<<<1, 256, 0, stream>>>(cnt_part, psum_part, cnt, offs, cursor, out + (out_size - 1));
  scatter_kernel<<<NASSIGN / 256, 256, 0, stream>>>(assign_e, offs, cursor, slot_tok, slot_of);
  // gemm1: M=cn x N=4096 x K=1024; rt-inner decode (balanced + B-panel L2 share)
  gemm8p<D_MODEL, D_FF, 12, 0, false><<<8 * 16 * 12, 512, 131072, stream>>>(
      xb, w1t, b1, slot_tok, cnt, offs, H);
  // gemm2: M=cn x N=1024 x K=4096; rt-OUTER decode (first 256 bids = the 256 real tiles)
  gemm8p<D_FF, D_MODEL, 12, 1, true><<<8 * 4 * 12, 512, 131072, stream>>>(
      H, w2t, b2, slot_tok, cnt, offs, y);
  combine_kernel<<<NTOK / 4, 256, 0, stream>>>((const unsigned short*)y, slot_of, assign_w, out);
}

// Round 22
// 526.180 us; speedup vs baseline: 1.0108x; 1.0108x over previous
//
#include <hip/hip_runtime.h>
#include <math.h>

#define D_MODEL 1024
#define D_FF    4096
#define NEXP    8
#define NTOK    8192
#define NASSIGN (NTOK*2)
#define NGBLK   (NTOK/4)   // gating blocks (4 tokens/block)

using short8 = __attribute__((ext_vector_type(8))) short;
using short4v = __attribute__((ext_vector_type(4))) short;
using f32x4  = __attribute__((ext_vector_type(4))) float;

__device__ __forceinline__ short f2bf(float f) {
  unsigned u = __float_as_uint(f);
  unsigned r = (u + 0x7fffu + ((u >> 16) & 1u)) >> 16;
  return (short)r;
}
__device__ __forceinline__ float bf2f(unsigned short u) {
  return __uint_as_float(((unsigned)u) << 16);
}

__device__ __forceinline__ void gload_lds16(const void* g, void* l) {
  __builtin_amdgcn_global_load_lds((const __attribute__((address_space(1))) void*)g,
                                   (__attribute__((address_space(3))) void*)l, 16, 0, 0);
}

// fast erf-gelu: Abramowitz-Stegun 7.1.26, |eps| <= 1.5e-7
__device__ __forceinline__ float gelu_f(float x) {
  float z = 0.70710678118f * x;
  float a = fabsf(z);
  float t = 1.0f / (1.0f + 0.3275911f * a);
  float p = t * (0.254829592f + t * (-0.284496736f + t * (1.421413741f +
            t * (-1.453152027f + t * 1.061405429f))));
  float er = 1.0f - p * __expf(-a * a);
  er = copysignf(er, z);
  return 0.5f * x * (1.0f + er);
}

// ========== fused prologue: W1-transpose | W2-transpose | gating, by blockIdx range ==========
__global__ __launch_bounds__(256) void prologue_kernel(
    const float* __restrict__ W1, short* __restrict__ w1t,
    const float* __restrict__ W2, short* __restrict__ w2t,
    const float* __restrict__ x, const float* __restrict__ Wg,
    int* __restrict__ assign_e, float* __restrict__ assign_w,
    int* __restrict__ cnt_part, float* __restrict__ psum_part,
    ushort4* __restrict__ xb4)
{
  __shared__ float t[64][70];          // transpose slab (17.9 KB)
  __shared__ float l_ps[NEXP];         // gating partials (coexist, tiny)
  __shared__ int   l_cnt[NEXP];
  int bid = blockIdx.x;
  int tid = threadIdx.x;

  if (bid < 16384) {
    // ---------------- transpose + convert (float2 loads, pad-70, full-line stores) ----------------
    const float* in; short* out; int R, C, cx, cy, e;
    if (bid < 8192) { in = W1; out = w1t; R = D_MODEL; C = D_FF;
                      cx = bid & 63; cy = (bid >> 6) & 15; e = bid >> 10; }
    else            { int lb = bid - 8192; in = W2; out = w2t; R = D_FF; C = D_MODEL;
                      cx = lb & 15;  cy = (lb >> 4) & 63;  e = lb >> 10; }
    size_t base = (size_t)e * R * C;
    int r0 = cy * 64, c0 = cx * 64;
    int lr = tid >> 5, lc2 = tid & 31;
#pragma unroll
    for (int j = 0; j < 8; ++j) {
      int rr = lr + j * 8;
      float2 v = *(const float2*)&in[base + (size_t)(r0 + rr) * C + c0 + lc2 * 2];
      *(float2*)&t[rr][lc2 * 2] = v;
    }
    __syncthreads();
#pragma unroll
    for (int p = 0; p < 2; ++p) {
      int oc = p * 32 + (tid >> 3);       // output row (input col)
      int rseg = (tid & 7) * 8;           // 8 consecutive R-elements
      short8 v;
#pragma unroll
      for (int q = 0; q < 8; ++q) v[q] = f2bf(t[rseg + q][oc]);
      *(short8*)&out[base + (size_t)(c0 + oc) * R + r0 + rseg] = v;
    }
    return;
  }

  // ---------------- gating: one wave per token; also emits xb (bf16 copy of x) ----------------
  int gb = bid - 16384;
  int wv = tid >> 6, lane = tid & 63;
  if (tid < NEXP) { l_ps[tid] = 0.f; l_cnt[tid] = 0; }
  __syncthreads();

  int tk = gb * 4 + wv;
  const float4* xr = (const float4*)(x + (size_t)tk * D_MODEL);
  float acc[NEXP];
#pragma unroll
  for (int e = 0; e < NEXP; ++e) acc[e] = 0.f;
#pragma unroll
  for (int i = 0; i < 4; ++i) {
    int c4 = lane + 64 * i;
    float4 v = xr[c4];
    ushort4 o;
    o.x = (unsigned short)f2bf(v.x); o.y = (unsigned short)f2bf(v.y);
    o.z = (unsigned short)f2bf(v.z); o.w = (unsigned short)f2bf(v.w);
    xb4[(size_t)tk * 256 + c4] = o;
    const float* wr = Wg + c4 * 4 * NEXP;
#pragma unroll
    for (int j = 0; j < 4; ++j) {
      float xv = (&v.x)[j];
#pragma unroll
      for (int e = 0; e < NEXP; ++e) acc[e] += xv * wr[j * NEXP + e];
    }
  }
#pragma unroll
  for (int off = 32; off; off >>= 1)
#pragma unroll
    for (int e = 0; e < NEXP; ++e) acc[e] += __shfl_down(acc[e], off);

  if (lane == 0) {
    float m = acc[0];
#pragma unroll
    for (int e = 1; e < NEXP; ++e) m = fmaxf(m, acc[e]);
    float p[NEXP], s = 0.f;
#pragma unroll
    for (int e = 0; e < NEXP; ++e) { p[e] = expf(acc[e] - m); s += p[e]; }
    float inv = 1.f / s;
#pragma unroll
    for (int e = 0; e < NEXP; ++e) p[e] *= inv;
    int i0 = 0; float v0 = p[0];
#pragma unroll
    for (int e = 1; e < NEXP; ++e) if (p[e] > v0) { v0 = p[e]; i0 = e; }
    int i1 = -1; float v1 = -1.f;
#pragma unroll
    for (int e = 0; e < NEXP; ++e) if (e != i0 && p[e] > v1) { v1 = p[e]; i1 = e; }
    float denom = 1.f / (v0 + v1 + 1e-9f);
    assign_e[2 * tk] = i0;     assign_w[2 * tk] = v0 * denom;
    assign_e[2 * tk + 1] = i1; assign_w[2 * tk + 1] = v1 * denom;
    atomicAdd(&l_cnt[i0], 1);
    atomicAdd(&l_cnt[i1], 1);
#pragma unroll
    for (int e = 0; e < NEXP; ++e) atomicAdd(&l_ps[e], p[e]);
  }
  __syncthreads();
  if (tid < NEXP) {
    psum_part[gb * NEXP + tid] = l_ps[tid];
    cnt_part[gb * NEXP + tid] = l_cnt[tid];
  }
}

// ---------------- scan: reduce partials -> cnt/offs + cursor zero + aux loss ----------------
__global__ __launch_bounds__(256) void scan_kernel(const int* __restrict__ cnt_part, const float* __restrict__ psum_part,
                                                   int* __restrict__ cnt, int* __restrict__ offs,
                                                   int* __restrict__ cursor, float* __restrict__ aux_out) {
  __shared__ float sp[256];
  __shared__ int   sc[256];
  int tid = threadIdx.x;
  int e = tid & 7, c = tid >> 3;
  float fs = 0.f; int is = 0;
  for (int b = c; b < NGBLK; b += 32) {
    fs += psum_part[b * NEXP + e];
    is += cnt_part[b * NEXP + e];
  }
  sp[tid] = fs; sc[tid] = is;
  __syncthreads();
  if (tid < NEXP) {
    float f = 0.f; int n = 0;
    for (int c2 = 0; c2 < 32; ++c2) { f += sp[c2 * 8 + tid]; n += sc[c2 * 8 + tid]; }
    cnt[tid] = n; sp[tid] = f;
    cursor[tid] = 0;
  }
  __syncthreads();
  if (tid == 0) {
    int o = 0; float aux = 0.f;
    for (int e2 = 0; e2 < NEXP; ++e2) {
      offs[e2] = o; o += cnt[e2];
      aux += (float)cnt[e2] * sp[e2];
    }
    aux_out[0] = aux * (float)NEXP / ((float)NTOK * (float)NTOK);
  }
}

// ---------------- scatter: compact assignments per expert ----------------
__global__ __launch_bounds__(256) void scatter_kernel(const int* __restrict__ assign_e,
                                                      const int* __restrict__ offs, int* __restrict__ cursor,
                                                      int* __restrict__ slot_tok, int* __restrict__ slot_of) {
  __shared__ int lhist[NEXP], lbase[NEXP];
  int tid = threadIdx.x;
  int a = blockIdx.x * 256 + tid;
  if (tid < NEXP) lhist[tid] = 0;
  __syncthreads();
  int e = assign_e[a];
  int lp = atomicAdd(&lhist[e], 1);
  __syncthreads();
  if (tid < NEXP) lbase[tid] = atomicAdd(&cursor[tid], lhist[tid]);
  __syncthreads();
  int s = offs[e] + lbase[e] + lp;
  slot_tok[s] = a >> 1;
  slot_of[a] = s;
}

// ========== 256x256 8-phase GEMM, lead-7 / vmcnt(6), 8-barrier lockstep, NO setprio ==========
// R22 = exact revert to R20 (measured best: 526.9 us). R21's 3-barrier variant regressed
// (+5 us, FETCH +15 MB): wave drift de-synchronized staging and hurt L2 locality. The
// lockstep-barriers + no-setprio combination is the optimum of the explored space.
template<int KD, int ND, int RT, int EPI, bool RTOUT>
__global__ __launch_bounds__(512, 2) void gemm8p(
    const short* __restrict__ Asrc, const short* __restrict__ Bsrc,
    const float* __restrict__ bias, const int* __restrict__ slot_tok,
    const int* __restrict__ cnt, const int* __restrict__ offs,
    short* __restrict__ OutP)
{
  constexpr int NT = KD / 64;          // K-tiles
  constexpr int NP = ND / 256;         // N panels
  constexpr int NPAN = NEXP * NP / 8;  // panels per XCD
  extern __shared__ char ldsb[];       // [buf][A 32K | B 32K]

  int bid = blockIdx.x;
  int x = bid & 7, j = bid >> 3;
  int k, rt;
  if (RTOUT) { rt = j / NPAN; k = j - rt * NPAN; }   // duds trail the grid
  else       { k = j / RT;    rt = j - k * RT; }     // rt-inner: panel L2 sharing
  int ft = k % NP;
  int e = (x + k) & 7;
  int cn = cnt[e];
  if (rt * 256 >= cn) return;
  int off = offs[e];
  int tid = threadIdx.x, l = tid & 63, w = tid >> 6;
  int wm = w >> 2, wn = w & 3;         // 2M x 4N
  int l15 = l & 15, kh = l >> 4;

  // ---- staging sources: stripe s, row (tid>>3), chunk pre-swizzled ----
  int srw = tid >> 3;
  int swz = ((tid & 7) ^ (srw & 7)) * 8;   // shorts
  const short* ar[4];
  const short* br[4];
#pragma unroll
  for (int s = 0; s < 4; ++s) {
    int gr = rt * 256 + s * 64 + srw;
    int ic = gr < cn ? gr : cn - 1;
    if (EPI == 0) ar[s] = Asrc + (size_t)slot_tok[off + ic] * KD + swz;
    else          ar[s] = Asrc + (size_t)(off + ic) * KD + swz;
    br[s] = Bsrc + (size_t)e * ND * KD + (size_t)(ft * 256 + s * 64 + srw) * KD + swz;
  }

#define STAGE(P, TAU) do {                                                        \
    int _b = (TAU) & 1;                                                           \
    const short* _p0 = ((P) >= 2 ? ar : br)[(P) & 1];                             \
    const short* _p1 = ((P) >= 2 ? ar : br)[((P) & 1) + 2];                       \
    char* _d = ldsb + _b * 65536 + ((P) >= 2 ? 0 : 32768);                        \
    gload_lds16(_p0 + (size_t)(TAU) * 64, _d + ((P) & 1) * 8192 + tid * 16);      \
    gload_lds16(_p1 + (size_t)(TAU) * 64, _d + (((P) & 1) + 2) * 8192 + tid * 16);\
  } while (0)

  // ---- prologue: 7 half-tiles (tile0 all parts + tile1 P0,P1,P2) ----
  STAGE(0, 0); STAGE(1, 0); STAGE(2, 0); STAGE(3, 0);
  STAGE(0, 1); STAGE(1, 1); STAGE(2, 1);
  asm volatile("s_waitcnt vmcnt(6)" ::: "memory");  // tile0 (8 loads) landed
  __builtin_amdgcn_s_barrier();

  int cx0 = ((0 * 4 + kh) ^ (l15 & 7)) << 4;   // byte XOR-offset for kk=0
  int cx1 = ((1 * 4 + kh) ^ (l15 & 7)) << 4;   // kk=1
  int arow = (wm * 128 + l15) << 7;            // byte row base for A reads
  int brow = (wn * 64 + l15) << 7;
  f32x4 acc[8][4] = {};
  short8 bq0[4], bq1[4], afA[4], afB[4];

  for (int t = 0; t < NT; ++t) {
    const char* Ab = ldsb + (t & 1) * 65536;
    const char* Bb = Ab + 32768;
    // ---- tile-entry reads: ALL B (kk0 + kk1) + A(mh0,kk0) ----
#pragma unroll
    for (int n = 0; n < 4; ++n) bq0[n] = *(const short8*)(Bb + brow + (n << 11) + cx0);
#pragma unroll
    for (int n = 0; n < 4; ++n) bq1[n] = *(const short8*)(Bb + brow + (n << 11) + cx1);
#pragma unroll
    for (int m = 0; m < 4; ++m) afA[m] = *(const short8*)(Ab + arow + ((m * 16) << 7) + cx0);
    // ---- q0: stage P3(t+1); prefetch A(mh1,kk0); MFMA(bq0, afA -> acc[0..3]) ----
    if (t + 1 < NT) STAGE(3, t + 1);
#pragma unroll
    for (int m = 0; m < 4; ++m) afB[m] = *(const short8*)(Ab + arow + ((64 + m * 16) << 7) + cx0);
    __builtin_amdgcn_s_barrier();
#pragma unroll
    for (int m = 0; m < 4; ++m)
#pragma unroll
      for (int n = 0; n < 4; ++n)
        acc[m][n] = __builtin_amdgcn_mfma_f32_16x16x32_bf16(bq0[n], afA[m], acc[m][n], 0, 0, 0);
    __builtin_amdgcn_s_barrier();
    // ---- q1: stage P0(t+2); prefetch A(mh0,kk1); MFMA(bq0, afB -> acc[4..7]) ----
    if (t + 2 < NT) STAGE(0, t + 2);
#pragma unroll
    for (int m = 0; m < 4; ++m) afA[m] = *(const short8*)(Ab + arow + ((m * 16) << 7) + cx1);
    __builtin_amdgcn_s_barrier();
#pragma unroll
    for (int m = 0; m < 4; ++m)
#pragma unroll
      for (int n = 0; n < 4; ++n)
        acc[4 + m][n] = __builtin_amdgcn_mfma_f32_16x16x32_bf16(bq0[n], afB[m], acc[4 + m][n], 0, 0, 0);
    __builtin_amdgcn_s_barrier();
    // ---- q2: stage P1(t+2); prefetch A(mh1,kk1); MFMA(bq1, afA -> acc[0..3]) ----
    if (t + 2 < NT) STAGE(1, t + 2);
#pragma unroll
    for (int m = 0; m < 4; ++m) afB[m] = *(const short8*)(Ab + arow + ((64 + m * 16) << 7) + cx1);
    __builtin_amdgcn_s_barrier();
#pragma unroll
    for (int m = 0; m < 4; ++m)
#pragma unroll
      for (int n = 0; n < 4; ++n)
        acc[m][n] = __builtin_amdgcn_mfma_f32_16x16x32_bf16(bq1[n], afA[m], acc[m][n], 0, 0, 0);
    __builtin_amdgcn_s_barrier();
    // ---- q3: stage P2(t+2); MFMA(bq1, afB -> acc[4..7]); boundary vmcnt ----
    if (t + 2 < NT) STAGE(2, t + 2);
    __builtin_amdgcn_s_barrier();
#pragma unroll
    for (int m = 0; m < 4; ++m)
#pragma unroll
      for (int n = 0; n < 4; ++n)
        acc[4 + m][n] = __builtin_amdgcn_mfma_f32_16x16x32_bf16(bq1[n], afB[m], acc[4 + m][n], 0, 0, 0);
    if (t < NT - 2)       { asm volatile("s_waitcnt vmcnt(6)" ::: "memory"); }
    else if (t == NT - 2) { asm volatile("s_waitcnt vmcnt(0)" ::: "memory"); }
    __builtin_amdgcn_s_barrier();
  }
#undef STAGE

  // ---- epilogue: bf16 via per-wave DOUBLE LDS slab -> full-line 16B stores (EPI0 adds gelu) ----
  int ftb = ft * 256;
  f32x4 b4[4];
#pragma unroll
  for (int n = 0; n < 4; ++n) b4[n] = *(const f32x4*)&bias[e * ND + ftb + wn * 64 + n * 16 + kh * 4];

  char* slab0 = ldsb + w * 4096;       // per-wave 2 x 2 KB (alternating by mi&1)
#pragma unroll
  for (int mi = 0; mi < 8; ++mi) {
    char* slab = slab0 + (mi & 1) * 2048;
#pragma unroll
    for (int n = 0; n < 4; ++n) {
      short4v h;
#pragma unroll
      for (int jj = 0; jj < 4; ++jj) {
        float v = acc[mi][n][jj] + b4[n][jj];
        if (EPI == 0) v = gelu_f(v);
        h[jj] = f2bf(v);
      }
      int chunk = n * 2 + (kh >> 1);
      *(short4v*)(slab + l15 * 128 + ((chunk ^ (l15 & 7)) << 4) + ((kh & 1) << 3)) = h;
    }
    int tr = l >> 2;
    int tok = rt * 256 + wm * 128 + mi * 16 + tr;
    if (tok < cn) {
#pragma unroll
      for (int cc = 0; cc < 2; ++cc) {
        int c2 = (l & 3) * 2 + cc;
        short8 v = *(const short8*)(slab + tr * 128 + ((c2 ^ (tr & 7)) << 4));
        *(short8*)&OutP[(size_t)(off + tok) * ND + ftb + wn * 64 + c2 * 8] = v;
      }
    }
  }
}

// ---------------- combine: out[t] = w0*y[s0] + w1*y[s1]  (y is bf16; 4 tokens/block) ----------------
__global__ __launch_bounds__(256) void combine_kernel(const unsigned short* __restrict__ y,
                                                      const int* __restrict__ slot_of,
                                                      const float* __restrict__ assign_w, float* __restrict__ out) {
  int tb = blockIdx.x * 4;
#pragma unroll
  for (int q = 0; q < 4; ++q) {
    int t = tb + q;
    int d4 = threadIdx.x;
    int s0 = slot_of[2 * t], s1 = slot_of[2 * t + 1];
    float w0 = assign_w[2 * t], w1 = assign_w[2 * t + 1];
    ushort4 a = ((const ushort4*)(y + (size_t)s0 * D_MODEL))[d4];
    ushort4 b = ((const ushort4*)(y + (size_t)s1 * D_MODEL))[d4];
    float4 o;
    o.x = w0 * bf2f(a.x) + w1 * bf2f(b.x);
    o.y = w0 * bf2f(a.y) + w1 * bf2f(b.y);
    o.z = w0 * bf2f(a.z) + w1 * bf2f(b.z);
    o.w = w0 * bf2f(a.w) + w1 * bf2f(b.w);
    ((float4*)(out + (size_t)t * D_MODEL))[d4] = o;
  }
}

extern "C" void kernel_launch(void* const* d_in, const int* in_sizes, int n_in,
                              void* d_out, int out_size, void* d_ws, size_t ws_size,
                              hipStream_t stream) {
  const float* x  = (const float*)d_in[0];
  const float* Wg = (const float*)d_in[1];
  const float* W1 = (const float*)d_in[2];
  const float* b1 = (const float*)d_in[3];
  const float* W2 = (const float*)d_in[4];
  const float* b2 = (const float*)d_in[5];
  float* out = (float*)d_out;
  char* ws = (char*)d_ws;

  // workspace layout (~285.6 MB)
  short* xb       = (short*)(ws);                       // 16,777,216 B
  short* w1t      = (short*)(ws + 16777216);            // 67,108,864 B  [e][f][k] bf16
  short* y        = (short*)(ws + 16777216);            // aliases w1t (dead after gemm1): 16384x1024 bf16
  short* w2t      = (short*)(ws + 83886080);            // 67,108,864 B  [e][d][ff] bf16
  short* H        = (short*)(ws + 150994944);           // 134,217,728 B 16384 x 4096 bf16
  int*   slot_tok = (int*)  (ws + 285212672);
  int*   assign_e = (int*)  (ws + 285278208);
  float* assign_w = (float*)(ws + 285343744);
  int*   slot_of  = (int*)  (ws + 285409280);
  int*   cnt_part = (int*)  (ws + 285474816);
  float* psum_part= (float*)(ws + 285540352);
  int*   ctrl     = (int*)  (ws + 285605888);
  int* cnt = ctrl; int* cursor = ctrl + 8; int* offs = ctrl + 16;

  hipFuncSetAttribute(reinterpret_cast<const void*>(&gemm8p<D_MODEL, D_FF, 12, 0, false>),
                      hipFuncAttributeMaxDynamicSharedMemorySize, 131072);
  hipFuncSetAttribute(reinterpret_cast<const void*>(&gemm8p<D_FF, D_MODEL, 12, 1, true>),
                      hipFuncAttributeMaxDynamicSharedMemorySize, 131072);

  // fused prologue: 8192 W1-tiles + 8192 W2-tiles + 2048 gating blocks = 18432 blocks, 1 launch
  prologue_kernel<<<16384 + NGBLK, 256, 0, stream>>>(W1, w1t, W2, w2t, x, Wg,
                                                     assign_e, assign_w, cnt_part, psum_part,
                                                     (ushort4*)xb);
  scan_kernel<<<1, 256, 0, stream>>>(cnt_part, psum_part, cnt, offs, cursor, out + (out_size - 1));
  scatter_kernel<<<NASSIGN / 256, 256, 0, stream>>>(assign_e, offs, cursor, slot_tok, slot_of);
  // gemm1: M=cn x N=4096 x K=1024; rt-inner decode (balanced + B-panel L2 share)
  gemm8p<D_MODEL, D_FF, 12, 0, false><<<8 * 16 * 12, 512, 131072, stream>>>(
      xb, w1t, b1, slot_tok, cnt, offs, H);
  // gemm2: M=cn x N=1024 x K=4096; rt-OUTER decode (first 256 bids = the 256 real tiles)
  gemm8p<D_FF, D_MODEL, 12, 1, true><<<8 * 4 * 12, 512, 131072, stream>>>(
      H, w2t, b2, slot_tok, cnt, offs, y);
  combine_kernel<<<NTOK / 4, 256, 0, stream>>>((const unsigned short*)y, slot_of, assign_w, out);
}